// Round 1
// baseline (318.864 us; speedup 1.0000x reference)
//
#include <hip/hip_runtime.h>
#include <math.h>

#define KK      7
#define C1      21
#define NPLANES (KK * KK * C1)   // 1029
#define H       100
#define W       100
#define HP      101
#define WP      101

// ---------------------------------------------------------------------------
// Kernel 1: build padded 2-D integral images for all 1029 planes of the LAST
// batch element.  integ[p][y][x] = sum of feat[p][y'<y][x'<x], p = (j*7+l)*21+c.
// One block per plane; plane staged in LDS (stride WP=101 to dodge bank
// conflicts on the row scan).
// ---------------------------------------------------------------------------
__global__ __launch_bounds__(128) void build_integral(
    const float* __restrict__ src,   // full cls_conv_out
    size_t batch_off,                // offset of last batch element (elements)
    float* __restrict__ integ)       // NPLANES * HP * WP floats
{
    const int p = blockIdx.x;
    const float* plane = src + batch_off + (size_t)p * (H * W);
    float* out = integ + (size_t)p * (HP * WP);

    __shared__ float tile[H][WP];    // 100 x 101 floats = 40.4 KB

    // coalesced load of the plane into LDS
    for (int i = threadIdx.x; i < H * W; i += blockDim.x) {
        int y = i / W, x = i - y * W;
        tile[y][x] = plane[i];
    }
    __syncthreads();

    // row prefix sums: thread t scans row t
    if (threadIdx.x < H) {
        int y = threadIdx.x;
        float s = 0.f;
        for (int x = 0; x < W; ++x) { s += tile[y][x]; tile[y][x] = s; }
    }
    __syncthreads();

    // column prefix sums + write padded output; thread t scans column t.
    if (threadIdx.x < W) {
        int x = threadIdx.x;
        out[x + 1] = 0.f;            // row 0, cols 1..100
        float s = 0.f;
        for (int y = 0; y < H; ++y) {
            s += tile[y][x];
            out[(y + 1) * WP + (x + 1)] = s;
        }
    }
    // column 0 (rows 0..100) = 0   (also covers out[0])
    for (int i = threadIdx.x; i < HP; i += blockDim.x) {
        out[(size_t)i * WP] = 0.f;
    }
}

// ---------------------------------------------------------------------------
// Kernel 2: per-ROI pooled mean + softmax via 4 integral lookups per
// (j,l,c) triple.  One block per ROI.
// ---------------------------------------------------------------------------
__global__ __launch_bounds__(256) void roi_pool_softmax(
    const float* __restrict__ integ,
    const int*   __restrict__ rois,
    float*       __restrict__ out)
{
    const int n = blockIdx.x;
    const int t = threadIdx.x;

    __shared__ float chsum[C1];
    if (t < C1) chsum[t] = 0.f;
    __syncthreads();

    const int ymin = rois[4 * n + 0];
    const int xmin = rois[4 * n + 1];
    const int ymax = rois[4 * n + 2];
    const int xmax = rois[4 * n + 3];
    const int ys = (ymax - ymin) / KK;   // in [1,8]
    const int xs = (xmax - xmin) / KK;   // in [1,8]

    for (int idx = t; idx < NPLANES; idx += blockDim.x) {
        const int c  = idx % C1;
        const int jl = idx / C1;
        const int l  = jl % KK;
        const int j  = jl / KK;
        const int y0 = ymin + j * ys, y1 = y0 + ys;
        const int x0 = xmin + l * xs, x1 = x0 + xs;
        const float* I = integ + (size_t)idx * (HP * WP);
        const float S = I[y1 * WP + x1] - I[y0 * WP + x1]
                      - I[y1 * WP + x0] + I[y0 * WP + x0];
        atomicAdd(&chsum[c], S);
    }
    __syncthreads();

    if (t == 0) {
        const float inv = 1.0f / (49.0f * (float)(ys * xs));
        float m = -INFINITY;
        for (int c = 0; c < C1; ++c) {
            float v = chsum[c] * inv;
            chsum[c] = v;
            m = fmaxf(m, v);
        }
        float s = 0.f;
        for (int c = 0; c < C1; ++c) {
            float e = expf(chsum[c] - m);
            chsum[c] = e;
            s += e;
        }
        const float rs = 1.0f / s;
        for (int c = 0; c < C1; ++c) out[(size_t)n * C1 + c] = chsum[c] * rs;
    }
}

// ---------------------------------------------------------------------------
// Fallback (only if ws_size < 42 MB): direct rectangle summation, no
// integral image.
// ---------------------------------------------------------------------------
__global__ __launch_bounds__(256) void roi_pool_direct(
    const float* __restrict__ src,
    size_t batch_off,
    const int*   __restrict__ rois,
    float*       __restrict__ out)
{
    const int n = blockIdx.x;
    const int t = threadIdx.x;

    __shared__ float chsum[C1];
    if (t < C1) chsum[t] = 0.f;
    __syncthreads();

    const int ymin = rois[4 * n + 0];
    const int xmin = rois[4 * n + 1];
    const int ymax = rois[4 * n + 2];
    const int xmax = rois[4 * n + 3];
    const int ys = (ymax - ymin) / KK;
    const int xs = (xmax - xmin) / KK;

    const float* base = src + batch_off;

    for (int idx = t; idx < NPLANES; idx += blockDim.x) {
        const int c  = idx % C1;
        const int jl = idx / C1;
        const int l  = jl % KK;
        const int j  = jl / KK;
        const int y0 = ymin + j * ys;
        const int x0 = xmin + l * xs;
        const float* plane = base + (size_t)idx * (H * W);
        float s = 0.f;
        for (int y = y0; y < y0 + ys; ++y) {
            const float* row = plane + (size_t)y * W + x0;
            for (int x = 0; x < xs; ++x) s += row[x];
        }
        atomicAdd(&chsum[c], s);
    }
    __syncthreads();

    if (t == 0) {
        const float inv = 1.0f / (49.0f * (float)(ys * xs));
        float m = -INFINITY;
        for (int c = 0; c < C1; ++c) {
            float v = chsum[c] * inv;
            chsum[c] = v;
            m = fmaxf(m, v);
        }
        float s = 0.f;
        for (int c = 0; c < C1; ++c) {
            float e = expf(chsum[c] - m);
            chsum[c] = e;
            s += e;
        }
        const float rs = 1.0f / s;
        for (int c = 0; c < C1; ++c) out[(size_t)n * C1 + c] = chsum[c] * rs;
    }
}

extern "C" void kernel_launch(void* const* d_in, const int* in_sizes, int n_in,
                              void* d_out, int out_size, void* d_ws, size_t ws_size,
                              hipStream_t stream)
{
    const float* cls = (const float*)d_in[0];
    const int*   rois = (const int*)d_in[1];
    float*       out  = (float*)d_out;

    const int nrois = in_sizes[1] / 4;                         // 2000
    const size_t plane_elems = (size_t)NPLANES * H * W;        // 10.29 M
    const int B = (int)((size_t)in_sizes[0] / plane_elems);    // 4
    const size_t batch_off = (size_t)(B - 1) * plane_elems;

    const size_t need = (size_t)NPLANES * HP * WP * sizeof(float);  // ~42 MB
    if (ws_size >= need) {
        float* integ = (float*)d_ws;
        build_integral<<<NPLANES, 128, 0, stream>>>(cls, batch_off, integ);
        roi_pool_softmax<<<nrois, 256, 0, stream>>>(integ, rois, out);
    } else {
        roi_pool_direct<<<nrois, 256, 0, stream>>>(cls, batch_off, rois, out);
    }
}

// Round 2
// 266.275 us; speedup vs baseline: 1.1975x; 1.1975x over previous
//
#include <hip/hip_runtime.h>
#include <math.h>

#define KK      7
#define C1      21
#define NPLANES (KK * KK * C1)   // 1029
#define H       100
#define W       100

// ---------------------------------------------------------------------------
// Kernel A (fused): one block per plane p=(j*7+l)*21+c of the LAST batch elem.
//  1. stage 100x100 plane in LDS (40 KB; 4 blocks/CU = 160 KB exact fit)
//  2. in-place 2-D inclusive integral (row scan + col scan)
//  3. all ROIs: 4 LDS lookups -> partial[n*NPLANES + p]
// ---------------------------------------------------------------------------
__global__ __launch_bounds__(256) void plane_partial(
    const float* __restrict__ src,   // full cls_conv_out
    size_t batch_off,                // offset of last batch element (elements)
    const int*  __restrict__ rois,   // [nrois][4] = ymin,xmin,ymax,xmax
    int nrois,
    float* __restrict__ partial)     // [nrois][NPLANES]
{
    const int p  = blockIdx.x;
    const int c  = p % C1;           (void)c;
    const int jl = p / C1;
    const int l  = jl % KK;
    const int j  = jl / KK;
    const int t  = threadIdx.x;

    __shared__ float tile[H * W];    // exactly 40000 B

    // 1. coalesced stage
    const float* plane = src + batch_off + (size_t)p * (H * W);
    for (int i = t; i < H * W; i += blockDim.x) tile[i] = plane[i];
    __syncthreads();

    // 2a. row-prefix: thread y scans row y (inclusive)
    if (t < H) {
        float s = 0.f;
        int base = t * W;
        for (int x = 0; x < W; ++x) { s += tile[base + x]; tile[base + x] = s; }
    }
    __syncthreads();

    // 2b. col-prefix: thread x scans column x (lane-consecutive -> conflict-free)
    if (t < W) {
        float s = 0.f;
        for (int y = 0; y < H; ++y) { s += tile[y * W + t]; tile[y * W + t] = s; }
    }
    __syncthreads();

    // 3. ROI lookups.  Inclusive integral I[y][x] = sum_{y'<=y, x'<=x}.
    //    rect rows [y0, y0+ys), cols [x0, x0+xs):
    //    S = I[y1][x1] - I[y0-1][x1] - I[y1][x0-1] + I[y0-1][x0-1]
    for (int n = t; n < nrois; n += blockDim.x) {
        const int4 r  = ((const int4*)rois)[n];   // ymin,xmin,ymax,xmax
        const int ys  = (r.z - r.x) / KK;
        const int xs  = (r.w - r.y) / KK;
        const int y0  = r.x + j * ys;
        const int x0  = r.y + l * xs;
        const int y1  = y0 + ys - 1;              // <= 94 < 100
        const int x1  = x0 + xs - 1;

        float S = tile[y1 * W + x1];
        if (x0 > 0)           S -= tile[y1 * W + (x0 - 1)];
        if (y0 > 0)           S -= tile[(y0 - 1) * W + x1];
        if (y0 > 0 && x0 > 0) S += tile[(y0 - 1) * W + (x0 - 1)];

        partial[(size_t)n * NPLANES + p] = S;
    }
}

// ---------------------------------------------------------------------------
// Kernel B: per ROI, reduce 1029 partials -> 21 channel sums, scale, softmax.
// ---------------------------------------------------------------------------
__global__ __launch_bounds__(256) void reduce_softmax(
    const float* __restrict__ partial,
    const int*   __restrict__ rois,
    float*       __restrict__ out)
{
    const int n = blockIdx.x;
    const int t = threadIdx.x;

    __shared__ float chsum[C1];
    if (t < C1) chsum[t] = 0.f;
    __syncthreads();

    const float* pp = partial + (size_t)n * NPLANES;
    for (int idx = t; idx < NPLANES; idx += blockDim.x) {
        atomicAdd(&chsum[idx % C1], pp[idx]);     // coalesced global read
    }
    __syncthreads();

    if (t == 0) {
        const int4 r  = ((const int4*)rois)[n];
        const int ys  = (r.z - r.x) / KK;
        const int xs  = (r.w - r.y) / KK;
        const float inv = 1.0f / (49.0f * (float)(ys * xs));

        float m = -INFINITY;
        float v[C1];
        for (int c = 0; c < C1; ++c) { v[c] = chsum[c] * inv; m = fmaxf(m, v[c]); }
        float s = 0.f;
        for (int c = 0; c < C1; ++c) { v[c] = expf(v[c] - m); s += v[c]; }
        const float rs = 1.0f / s;
        for (int c = 0; c < C1; ++c) out[(size_t)n * C1 + c] = v[c] * rs;
    }
}

// ---------------------------------------------------------------------------
// Fallback (ws too small): direct rectangle summation from global.
// ---------------------------------------------------------------------------
__global__ __launch_bounds__(256) void roi_pool_direct(
    const float* __restrict__ src,
    size_t batch_off,
    const int*   __restrict__ rois,
    float*       __restrict__ out)
{
    const int n = blockIdx.x;
    const int t = threadIdx.x;

    __shared__ float chsum[C1];
    if (t < C1) chsum[t] = 0.f;
    __syncthreads();

    const int ymin = rois[4 * n + 0];
    const int xmin = rois[4 * n + 1];
    const int ymax = rois[4 * n + 2];
    const int xmax = rois[4 * n + 3];
    const int ys = (ymax - ymin) / KK;
    const int xs = (xmax - xmin) / KK;

    const float* base = src + batch_off;

    for (int idx = t; idx < NPLANES; idx += blockDim.x) {
        const int c  = idx % C1;
        const int jl = idx / C1;
        const int l  = jl % KK;
        const int j  = jl / KK;
        const int y0 = ymin + j * ys;
        const int x0 = xmin + l * xs;
        const float* plane = base + (size_t)idx * (H * W);
        float s = 0.f;
        for (int y = y0; y < y0 + ys; ++y) {
            const float* row = plane + (size_t)y * W + x0;
            for (int x = 0; x < xs; ++x) s += row[x];
        }
        atomicAdd(&chsum[c], s);
    }
    __syncthreads();

    if (t == 0) {
        const float inv = 1.0f / (49.0f * (float)(ys * xs));
        float m = -INFINITY;
        float v[C1];
        for (int c = 0; c < C1; ++c) { v[c] = chsum[c] * inv; m = fmaxf(m, v[c]); }
        float s = 0.f;
        for (int c = 0; c < C1; ++c) { v[c] = expf(v[c] - m); s += v[c]; }
        const float rs = 1.0f / s;
        for (int c = 0; c < C1; ++c) out[(size_t)n * C1 + c] = v[c] * rs;
    }
}

extern "C" void kernel_launch(void* const* d_in, const int* in_sizes, int n_in,
                              void* d_out, int out_size, void* d_ws, size_t ws_size,
                              hipStream_t stream)
{
    const float* cls  = (const float*)d_in[0];
    const int*   rois = (const int*)d_in[1];
    float*       out  = (float*)d_out;

    const int nrois = in_sizes[1] / 4;                         // 2000
    const size_t plane_elems = (size_t)NPLANES * H * W;        // 10.29 M
    const int B = (int)((size_t)in_sizes[0] / plane_elems);    // 4
    const size_t batch_off = (size_t)(B - 1) * plane_elems;

    const size_t need = (size_t)nrois * NPLANES * sizeof(float);  // ~8.2 MB
    if (ws_size >= need) {
        float* partial = (float*)d_ws;
        plane_partial<<<NPLANES, 256, 0, stream>>>(cls, batch_off, rois, nrois, partial);
        reduce_softmax<<<nrois, 256, 0, stream>>>(partial, rois, out);
    } else {
        roi_pool_direct<<<nrois, 256, 0, stream>>>(cls, batch_off, rois, out);
    }
}